// Round 5
// baseline (234.839 us; speedup 1.0000x reference)
//
#include <hip/hip_runtime.h>

#define D_MODEL 1024
#define SEQ     2048
#define BATCH   2
#define NH      16
#define DK      64
#define MROWS   (BATCH*SEQ)   // 4096

typedef __attribute__((ext_vector_type(8))) short short8;   // 8 bf16 (4 VGPRs)
typedef __attribute__((ext_vector_type(4))) float f32x4;

// 1/sqrt(64) * log2(e): folded into Q projection so scores feed exp2 directly
#define QSCALE 0.18033688011112042f

#if __has_builtin(__builtin_amdgcn_exp2f)
#define EXP2(x) __builtin_amdgcn_exp2f(x)
#else
#define EXP2(x) exp2f(x)
#endif

static __device__ __forceinline__ unsigned short f2bf(float f) {
  unsigned u = __float_as_uint(f);
  u += 0x7fff + ((u >> 16) & 1);          // round-to-nearest-even
  return (unsigned short)(u >> 16);
}

// pack two fp32 -> two bf16 (round-half-up) in 3 VALU via v_perm
static __device__ __forceinline__ unsigned pack_bf2(float a, float b) {
  unsigned ua = __float_as_uint(a) + 0x8000u;
  unsigned ub = __float_as_uint(b) + 0x8000u;
#if __has_builtin(__builtin_amdgcn_perm)
  return __builtin_amdgcn_perm(ub, ua, 0x07060302u);  // {ub.b3,ub.b2,ua.b3,ua.b2}
#else
  return (ua >> 16) | (ub & 0xffff0000u);
#endif
}

static __device__ __forceinline__ void load16_lds(const void* g, void* l) {
  __builtin_amdgcn_global_load_lds(
      (const __attribute__((address_space(1))) void*)g,
      (__attribute__((address_space(3))) void*)l, 16, 0, 0);
}

// ---------------- fp32 -> bf16 convert, all 3 tensors in one dispatch ----------------
__global__ void cvt_all(const float* __restrict__ q, const float* __restrict__ k,
                        const float* __restrict__ v, unsigned short* __restrict__ out, int n4) {
  int i = blockIdx.x * blockDim.x + threadIdx.x;
  if (i >= n4) return;
  const float* src = (blockIdx.y == 0) ? q : (blockIdx.y == 1) ? k : v;
  float4 val = ((const float4*)src)[i];
  unsigned r0 = (unsigned)f2bf(val.x) | ((unsigned)f2bf(val.y) << 16);
  unsigned r1 = (unsigned)f2bf(val.z) | ((unsigned)f2bf(val.w) << 16);
  uint2 u; u.x = r0; u.y = r1;
  ((uint2*)(out + (size_t)blockIdx.y * MROWS * D_MODEL))[i] = u;
}

// ------------- 4 weights [K,N] fp32 -> [N,K] bf16 in one dispatch -------------
__global__ void wtrans_all(const float* __restrict__ Wq, const float* __restrict__ Wk,
                           const float* __restrict__ Wv, const float* __restrict__ Wo,
                           unsigned short* __restrict__ Wt) {
  __shared__ float t[32][33];
  const float* W = (blockIdx.z == 0) ? Wq : (blockIdx.z == 1) ? Wk
                 : (blockIdx.z == 2) ? Wv : Wo;
  unsigned short* dst = Wt + (size_t)blockIdx.z * D_MODEL * D_MODEL;
  int n0 = blockIdx.x * 32, k0 = blockIdx.y * 32;
  int tx = threadIdx.x & 31, ty = threadIdx.x >> 5;
#pragma unroll
  for (int i = 0; i < 32; i += 8)
    t[ty + i][tx] = W[(size_t)(k0 + ty + i) * D_MODEL + n0 + tx];
  __syncthreads();
#pragma unroll
  for (int i = 0; i < 32; i += 8)
    dst[(size_t)(n0 + ty + i) * D_MODEL + k0 + tx] = f2bf(t[tx][ty + i]);
}

// ---------------- fused QKV projection GEMM (128x128 tiles) ----------------
// g = blockIdx.y>>5 selects input third / weight / bias / output.
// g==0: Q head-split, PRE-SCALED by QSCALE; g==1: K head-split; g==2: Vt [B,H,64,S].
// launch_bounds (256,3): cap VGPR at 170 so 3 blocks/CU co-reside (grid 768 = one round).
__global__ __launch_bounds__(256, 3) void gemm_qkv(
    const unsigned short* __restrict__ Abig,
    const unsigned short* __restrict__ Wt,
    const float* __restrict__ bq, const float* __restrict__ bk, const float* __restrict__ bv,
    unsigned short* __restrict__ Qh, unsigned short* __restrict__ Kh,
    unsigned short* __restrict__ Vt)
{
  constexpr int K = D_MODEL;
  __shared__ unsigned short As[128 * 32];
  __shared__ unsigned short Bs[128 * 32];
  const int g = blockIdx.y >> 5;
  const unsigned short* A  = Abig + (size_t)g * MROWS * K;
  const unsigned short* Bt = Wt + (size_t)g * K * K;
  const float* bias = (g == 0) ? bq : (g == 1) ? bk : bv;
  unsigned short* out = (g == 0) ? Qh : (g == 1) ? Kh : Vt;

  const int tid  = threadIdx.x;
  const int wave = tid >> 6, lane = tid & 63;
  const int quad = lane >> 4, l16 = lane & 15;
  const int bm = (blockIdx.y & 31) * 128, bn = blockIdx.x * 128;
  const int wm = (wave >> 1) * 64, wn = (wave & 1) * 64;
  const int srow = tid >> 2, scol = (tid & 3) * 8;

  f32x4 acc[4][4] = {};
  for (int k0 = 0; k0 < K; k0 += 32) {
    load16_lds(&A [(size_t)(bm      + srow) * K + k0 + scol], &As[tid * 8]);
    load16_lds(&A [(size_t)(bm + 64 + srow) * K + k0 + scol], &As[2048 + tid * 8]);
    load16_lds(&Bt[(size_t)(bn      + srow) * K + k0 + scol], &Bs[tid * 8]);
    load16_lds(&Bt[(size_t)(bn + 64 + srow) * K + k0 + scol], &Bs[2048 + tid * 8]);
    __syncthreads();
    short8 af[4], bfr[4];
#pragma unroll
    for (int i = 0; i < 4; ++i) {
      af[i]  = *(const short8*)&As[(wm + i * 16 + l16) * 32 + quad * 8];
      bfr[i] = *(const short8*)&Bs[(wn + i * 16 + l16) * 32 + quad * 8];
    }
#pragma unroll
    for (int mt = 0; mt < 4; ++mt)
#pragma unroll
      for (int nt = 0; nt < 4; ++nt)
        acc[mt][nt] = __builtin_amdgcn_mfma_f32_16x16x32_bf16(af[mt], bfr[nt], acc[mt][nt], 0, 0, 0);
    __syncthreads();
  }

  if (g == 2) {
    // V epilogue: transpose 16x16 subtiles through LDS -> Vt [B,H,64,S]
    float* tb = (float*)As + wave * 272;
#pragma unroll
    for (int mt = 0; mt < 4; ++mt)
#pragma unroll
      for (int nt = 0; nt < 4; ++nt) {
        int nbase = bn + wn + nt * 16;
        float bvv = bias[nbase + l16];
#pragma unroll
        for (int r = 0; r < 4; ++r)
          tb[(quad * 4 + r) * 17 + l16] = acc[mt][nt][r] + bvv;
        float v2[4];
#pragma unroll
        for (int r2 = 0; r2 < 4; ++r2)
          v2[r2] = tb[l16 * 17 + quad * 4 + r2];
        int m = bm + wm + mt * 16 + l16;
        int bb = m >> 11, s = m & 2047;
#pragma unroll
        for (int r2 = 0; r2 < 4; ++r2) {
          int n = nbase + quad * 4 + r2;
          int h = n >> 6, d = n & 63;
          out[((size_t)(bb * NH + h) * DK + d) * SEQ + s] = f2bf(v2[r2]);
        }
      }
    return;
  }

  const float scl = (g == 0) ? QSCALE : 1.0f;
#pragma unroll
  for (int mt = 0; mt < 4; ++mt)
#pragma unroll
    for (int nt = 0; nt < 4; ++nt) {
      int n = bn + wn + nt * 16 + l16;
      float bvv = bias[n];
#pragma unroll
      for (int r = 0; r < 4; ++r) {
        int m = bm + wm + mt * 16 + quad * 4 + r;
        float v = (acc[mt][nt][r] + bvv) * scl;
        int b = m >> 11, s = m & 2047;
        int h = n >> 6,  d = n & 63;
        out[((size_t)(b * NH + h) * SEQ + s) * DK + d] = f2bf(v);
      }
    }
}

// ---------------- output projection GEMM, 128x64 tiles (grid 512) ----------------
__global__ __launch_bounds__(256, 2) void gemm_out(
    const unsigned short* __restrict__ A,
    const unsigned short* __restrict__ Bt,
    const float* __restrict__ bias,
    float* __restrict__ out)
{
  constexpr int K = D_MODEL;
  __shared__ unsigned short As[128 * 32];
  __shared__ unsigned short Bs[64 * 32];
  const int tid  = threadIdx.x;
  const int wave = tid >> 6, lane = tid & 63;
  const int quad = lane >> 4, l16 = lane & 15;
  const int bm = blockIdx.y * 128, bn = blockIdx.x * 64;
  const int wm = (wave >> 1) * 64, wn = (wave & 1) * 32;
  const int srow = tid >> 2, scol = (tid & 3) * 8;

  f32x4 acc[4][2] = {};
  for (int k0 = 0; k0 < K; k0 += 32) {
    load16_lds(&A [(size_t)(bm      + srow) * K + k0 + scol], &As[tid * 8]);
    load16_lds(&A [(size_t)(bm + 64 + srow) * K + k0 + scol], &As[2048 + tid * 8]);
    load16_lds(&Bt[(size_t)(bn      + srow) * K + k0 + scol], &Bs[tid * 8]);
    __syncthreads();
    short8 af[4], bfr[2];
#pragma unroll
    for (int i = 0; i < 4; ++i)
      af[i]  = *(const short8*)&As[(wm + i * 16 + l16) * 32 + quad * 8];
#pragma unroll
    for (int i = 0; i < 2; ++i)
      bfr[i] = *(const short8*)&Bs[(wn + i * 16 + l16) * 32 + quad * 8];
#pragma unroll
    for (int mt = 0; mt < 4; ++mt)
#pragma unroll
      for (int nt = 0; nt < 2; ++nt)
        acc[mt][nt] = __builtin_amdgcn_mfma_f32_16x16x32_bf16(af[mt], bfr[nt], acc[mt][nt], 0, 0, 0);
    __syncthreads();
  }
#pragma unroll
  for (int mt = 0; mt < 4; ++mt)
#pragma unroll
    for (int nt = 0; nt < 2; ++nt) {
      int n = bn + wn + nt * 16 + l16;
      float bvv = bias[n];
#pragma unroll
      for (int r = 0; r < 4; ++r) {
        int m = bm + wm + mt * 16 + quad * 4 + r;
        out[(size_t)m * D_MODEL + n] = acc[mt][nt][r] + bvv;
      }
    }
}

// ---------------- flash attention v5: 64-row Q tiles, 4 blocks/CU ----------------
// Grid 1024 (32 bh x 32 qtiles). Each wave owns 16 Q rows. LDS exactly 40960 B
// (Ks 16K dbuf + Vs 16K dbuf + Ps 8K wave-private) -> 4 blocks/CU, 16 waves/CU.
// No-max softmax: p = exp2(s) (scores pre-scaled in Q projection), per-lane
// denominator, zero in-loop cross-lane ops, 1 barrier/chunk.
__global__ __launch_bounds__(256) void attn(
    const unsigned short* __restrict__ Qh,
    const unsigned short* __restrict__ Kh,
    const unsigned short* __restrict__ Vt,
    unsigned short* __restrict__ ctx)
{
  const int blk = blockIdx.x;
  const int bh = blk >> 5, qt = blk & 31;   // 32 consecutive blocks share bh (L2 reuse)
  const int tid = threadIdx.x, wave = tid >> 6, lane = tid & 63;
  const int quad = lane >> 4, l16 = lane & 15;
  const int r0 = tid >> 3, u = tid & 7;

  __shared__ unsigned short Ks[2][64 * 64];   // 16 KB  [key][d] swizzled
  __shared__ unsigned short Vs[2][64 * 64];   // 16 KB  [d][key] swizzled
  __shared__ unsigned short Ps[4][16 * 64];   // 8 KB   wave-private [qrow][key] swizzled

  const unsigned short* Kbase = Kh + (size_t)bh * SEQ * DK;
  const unsigned short* Vbase = Vt + (size_t)bh * DK * SEQ;
  const unsigned short* Qp = Qh + ((size_t)bh * SEQ + qt * 64 + wave * 16) * DK;

  // Q as MFMA B-operand: B[n=qrow(l16)][k=d(quad*8+j)]
  short8 aq0 = *(const short8*)&Qp[l16 * DK + quad * 8];
  short8 aq1 = *(const short8*)&Qp[l16 * DK + 32 + quad * 8];

  f32x4 cacc[4] = {};           // ctx: row=qrow local (quad*4+r), col=d (dt*16+l16)
  float lacc = 0.f;             // per-lane partial denominator for qrow l16

  const int koff0 = ((quad + l16) & 7) * 8;
  const int koff1 = ((4 + quad + l16) & 7) * 8;

  short8 sk0, sk1, sv0, sv1;
  auto stage_load = [&](int c) {
    const unsigned short* kg = Kbase + ((size_t)(c * 64 + r0)) * DK + u * 8;
    sk0 = *(const short8*)kg;
    sk1 = *(const short8*)(kg + (size_t)32 * DK);
    const unsigned short* vg = Vbase + (size_t)r0 * SEQ + c * 64 + u * 8;
    sv0 = *(const short8*)vg;
    sv1 = *(const short8*)(vg + (size_t)32 * SEQ);
  };
  auto stage_write = [&](int b) {
    int p = ((u + r0) & 7) * 8;
    *(short8*)&Ks[b][r0 * 64 + p]        = sk0;
    *(short8*)&Ks[b][(r0 + 32) * 64 + p] = sk1;
    *(short8*)&Vs[b][r0 * 64 + p]        = sv0;
    *(short8*)&Vs[b][(r0 + 32) * 64 + p] = sv1;
  };

  stage_load(0); stage_write(0);
  __syncthreads();

  for (int c = 0; c < SEQ / 64; ++c) {
    const int buf = c & 1;
    const bool pre = (c + 1 < SEQ / 64);
    if (pre) stage_load(c + 1);

    // ---- Sᵀ[key][qrow]: A=K frag (m=key), B=Q frag (n=qrow)
    f32x4 s_[4] = {};
#pragma unroll
    for (int kt = 0; kt < 4; ++kt) {
      short8 kb0 = *(const short8*)&Ks[buf][(kt * 16 + l16) * 64 + koff0];
      short8 kb1 = *(const short8*)&Ks[buf][(kt * 16 + l16) * 64 + koff1];
      s_[kt] = __builtin_amdgcn_mfma_f32_16x16x32_bf16(kb0, aq0, s_[kt], 0, 0, 0);
      s_[kt] = __builtin_amdgcn_mfma_f32_16x16x32_bf16(kb1, aq1, s_[kt], 0, 0, 0);
    }

    // ---- p = exp2(s); accumulate denominator; pack to wave-private LDS
    float p[4][4];
#pragma unroll
    for (int kt = 0; kt < 4; ++kt)
#pragma unroll
      for (int r = 0; r < 4; ++r)
        p[kt][r] = EXP2(s_[kt][r]);
    {
      float t0 = (p[0][0] + p[0][1]) + (p[0][2] + p[0][3]);
      float t1 = (p[1][0] + p[1][1]) + (p[1][2] + p[1][3]);
      float t2 = (p[2][0] + p[2][1]) + (p[2][2] + p[2][3]);
      float t3 = (p[3][0] + p[3][1]) + (p[3][2] + p[3][3]);
      lacc += (t0 + t1) + (t2 + t3);
    }
#pragma unroll
    for (int kt = 0; kt < 4; ++kt) {
      uint2 pk;
      pk.x = pack_bf2(p[kt][0], p[kt][1]);
      pk.y = pack_bf2(p[kt][2], p[kt][3]);
      int pos16 = (kt * 2 + (quad >> 1) + l16) & 7;
      *(uint2*)&Ps[wave][l16 * 64 + pos16 * 8 + (quad & 1) * 4] = pk;
    }

    // ---- PV: ctx[qrow][d] += P[qrow][key] V[key][d]
    {
      short8 ap0 = *(const short8*)&Ps[wave][l16 * 64 + koff0];
      short8 ap1 = *(const short8*)&Ps[wave][l16 * 64 + koff1];
#pragma unroll
      for (int dt = 0; dt < 4; ++dt) {
        short8 vb0 = *(const short8*)&Vs[buf][(dt * 16 + l16) * 64 + koff0];
        short8 vb1 = *(const short8*)&Vs[buf][(dt * 16 + l16) * 64 + koff1];
        cacc[dt] = __builtin_amdgcn_mfma_f32_16x16x32_bf16(ap0, vb0, cacc[dt], 0, 0, 0);
        cacc[dt] = __builtin_amdgcn_mfma_f32_16x16x32_bf16(ap1, vb1, cacc[dt], 0, 0, 0);
      }
    }

    if (pre) {
      stage_write(buf ^ 1);
      __syncthreads();
    }
  }

  // ---- epilogue: reduce l across quads, per-lane shfl broadcast, store
  lacc += __shfl_xor(lacc, 16);
  lacc += __shfl_xor(lacc, 32);
  const int b = bh >> 4, h = bh & 15;
  float lv[4];
#pragma unroll
  for (int r = 0; r < 4; ++r)
    lv[r] = 1.0f / __shfl(lacc, quad * 4 + r);
#pragma unroll
  for (int dt = 0; dt < 4; ++dt)
#pragma unroll
    for (int r = 0; r < 4; ++r) {
      int m = qt * 64 + wave * 16 + quad * 4 + r;
      float v = cacc[dt][r] * lv[r];
      ctx[(size_t)(b * SEQ + m) * D_MODEL + h * DK + dt * 16 + l16] = f2bf(v);
    }
}

extern "C" void kernel_launch(void* const* d_in, const int* in_sizes, int n_in,
                              void* d_out, int out_size, void* d_ws, size_t ws_size,
                              hipStream_t stream) {
  const float* q  = (const float*)d_in[0];
  const float* k  = (const float*)d_in[1];
  const float* v  = (const float*)d_in[2];
  const float* Wq = (const float*)d_in[3];
  const float* bq = (const float*)d_in[4];
  const float* Wk = (const float*)d_in[5];
  const float* bk = (const float*)d_in[6];
  const float* Wv = (const float*)d_in[7];
  const float* bv = (const float*)d_in[8];
  const float* Wo = (const float*)d_in[9];
  const float* bo = (const float*)d_in[10];

  char* ws = (char*)d_ws;
  const size_t SZ_ACT = (size_t)MROWS * D_MODEL * 2;    // 8 MB
  const size_t SZ_W   = (size_t)D_MODEL * D_MODEL * 2;  // 2 MB
  unsigned short* qkvb = (unsigned short*)(ws);                    // 24 MB
  unsigned short* Wall = (unsigned short*)(ws + 3 * SZ_ACT);       // 8 MB
  unsigned short* Qh   = (unsigned short*)(ws + 3 * SZ_ACT + 4 * SZ_W);
  unsigned short* Kh   = (unsigned short*)(ws + 4 * SZ_ACT + 4 * SZ_W);
  unsigned short* Vt   = (unsigned short*)(ws + 5 * SZ_ACT + 4 * SZ_W);
  unsigned short* Wot  = Wall + 3 * (size_t)D_MODEL * D_MODEL;
  unsigned short* ctx  = qkvb;   // alias: qkv bf16 dead after projections

  int n4 = MROWS * D_MODEL / 4;
  cvt_all<<<dim3(n4 / 256, 3), 256, 0, stream>>>(q, k, v, qkvb, n4);
  wtrans_all<<<dim3(32, 32, 4), 256, 0, stream>>>(Wq, Wk, Wv, Wo, Wall);

  gemm_qkv<<<dim3(D_MODEL / 128, 96), 256, 0, stream>>>(qkvb, Wall, bq, bk, bv, Qh, Kh, Vt);

  attn<<<dim3(32 * 32), 256, 0, stream>>>(Qh, Kh, Vt, ctx);

  gemm_out<<<dim3(D_MODEL / 64, MROWS / 128), 256, 0, stream>>>(ctx, Wot, bo, (float*)d_out);
}

// Round 6
// 225.596 us; speedup vs baseline: 1.0410x; 1.0410x over previous
//
#include <hip/hip_runtime.h>

#define D_MODEL 1024
#define SEQ     2048
#define BATCH   2
#define NH      16
#define DK      64
#define MROWS   (BATCH*SEQ)   // 4096

typedef __attribute__((ext_vector_type(8))) short short8;    // 8 bf16 (4 VGPRs)
typedef __attribute__((ext_vector_type(4))) float f32x4;
typedef __attribute__((ext_vector_type(16))) float f32x16;

// 1/sqrt(64) * log2(e): folded into Q projection so scores feed exp2 directly
#define QSCALE 0.18033688011112042f

#if __has_builtin(__builtin_amdgcn_exp2f)
#define EXP2(x) __builtin_amdgcn_exp2f(x)
#else
#define EXP2(x) exp2f(x)
#endif

static __device__ __forceinline__ unsigned short f2bf(float f) {
  unsigned u = __float_as_uint(f);
  u += 0x7fff + ((u >> 16) & 1);          // round-to-nearest-even
  return (unsigned short)(u >> 16);
}

// pack two fp32 -> two bf16 (round-half-up) in 3 VALU via v_perm
static __device__ __forceinline__ unsigned pack_bf2(float a, float b) {
  unsigned ua = __float_as_uint(a) + 0x8000u;
  unsigned ub = __float_as_uint(b) + 0x8000u;
#if __has_builtin(__builtin_amdgcn_perm)
  return __builtin_amdgcn_perm(ub, ua, 0x07060302u);  // {ub.b3,ub.b2,ua.b3,ua.b2}
#else
  return (ua >> 16) | (ub & 0xffff0000u);
#endif
}

// v_permlane32_swap_b32: x' = {x.lo32, y.lo32}, y' = {x.hi32, y.hi32}
static __device__ __forceinline__ void plswap(unsigned& x, unsigned& y, int h) {
#if __has_builtin(__builtin_amdgcn_permlane32_swap)
  typedef __attribute__((ext_vector_type(2))) unsigned uint2v;
  uint2v r = __builtin_amdgcn_permlane32_swap(x, y, false, false);
  x = r.x; y = r.y;
#else
  unsigned xs = __shfl_xor((int)x, 32), ys = __shfl_xor((int)y, 32);
  unsigned nx = h ? ys : x;
  unsigned ny = h ? y : xs;
  x = nx; y = ny;
#endif
}

static __device__ __forceinline__ void load16_lds(const void* g, void* l) {
  __builtin_amdgcn_global_load_lds(
      (const __attribute__((address_space(1))) void*)g,
      (__attribute__((address_space(3))) void*)l, 16, 0, 0);
}

// ---------------- fp32 -> bf16 convert, all 3 tensors in one dispatch ----------------
__global__ void cvt_all(const float* __restrict__ q, const float* __restrict__ k,
                        const float* __restrict__ v, unsigned short* __restrict__ out, int n4) {
  int i = blockIdx.x * blockDim.x + threadIdx.x;
  if (i >= n4) return;
  const float* src = (blockIdx.y == 0) ? q : (blockIdx.y == 1) ? k : v;
  float4 val = ((const float4*)src)[i];
  unsigned r0 = (unsigned)f2bf(val.x) | ((unsigned)f2bf(val.y) << 16);
  unsigned r1 = (unsigned)f2bf(val.z) | ((unsigned)f2bf(val.w) << 16);
  uint2 u; u.x = r0; u.y = r1;
  ((uint2*)(out + (size_t)blockIdx.y * MROWS * D_MODEL))[i] = u;
}

// ------------- 4 weights [K,N] fp32 -> [N,K] bf16 in one dispatch -------------
__global__ void wtrans_all(const float* __restrict__ Wq, const float* __restrict__ Wk,
                           const float* __restrict__ Wv, const float* __restrict__ Wo,
                           unsigned short* __restrict__ Wt) {
  __shared__ float t[32][33];
  const float* W = (blockIdx.z == 0) ? Wq : (blockIdx.z == 1) ? Wk
                 : (blockIdx.z == 2) ? Wv : Wo;
  unsigned short* dst = Wt + (size_t)blockIdx.z * D_MODEL * D_MODEL;
  int n0 = blockIdx.x * 32, k0 = blockIdx.y * 32;
  int tx = threadIdx.x & 31, ty = threadIdx.x >> 5;
#pragma unroll
  for (int i = 0; i < 32; i += 8)
    t[ty + i][tx] = W[(size_t)(k0 + ty + i) * D_MODEL + n0 + tx];
  __syncthreads();
#pragma unroll
  for (int i = 0; i < 32; i += 8)
    dst[(size_t)(n0 + ty + i) * D_MODEL + k0 + tx] = f2bf(t[tx][ty + i]);
}

// ---------------- fused QKV projection GEMM (128x128 tiles) ----------------
// g = blockIdx.y>>5 selects input third / weight / bias / output.
// g==0: Q head-split, PRE-SCALED by QSCALE; g==1: K head-split; g==2: Vt [B,H,64,S].
__global__ __launch_bounds__(256, 2) void gemm_qkv(
    const unsigned short* __restrict__ Abig,
    const unsigned short* __restrict__ Wt,
    const float* __restrict__ bq, const float* __restrict__ bk, const float* __restrict__ bv,
    unsigned short* __restrict__ Qh, unsigned short* __restrict__ Kh,
    unsigned short* __restrict__ Vt)
{
  constexpr int K = D_MODEL;
  __shared__ unsigned short As[128 * 32];
  __shared__ unsigned short Bs[128 * 32];
  const int g = blockIdx.y >> 5;
  const unsigned short* A  = Abig + (size_t)g * MROWS * K;
  const unsigned short* Bt = Wt + (size_t)g * K * K;
  const float* bias = (g == 0) ? bq : (g == 1) ? bk : bv;
  unsigned short* out = (g == 0) ? Qh : (g == 1) ? Kh : Vt;

  const int tid  = threadIdx.x;
  const int wave = tid >> 6, lane = tid & 63;
  const int quad = lane >> 4, l16 = lane & 15;
  const int bm = (blockIdx.y & 31) * 128, bn = blockIdx.x * 128;
  const int wm = (wave >> 1) * 64, wn = (wave & 1) * 64;
  const int srow = tid >> 2, scol = (tid & 3) * 8;

  f32x4 acc[4][4] = {};
  for (int k0 = 0; k0 < K; k0 += 32) {
    load16_lds(&A [(size_t)(bm      + srow) * K + k0 + scol], &As[tid * 8]);
    load16_lds(&A [(size_t)(bm + 64 + srow) * K + k0 + scol], &As[2048 + tid * 8]);
    load16_lds(&Bt[(size_t)(bn      + srow) * K + k0 + scol], &Bs[tid * 8]);
    load16_lds(&Bt[(size_t)(bn + 64 + srow) * K + k0 + scol], &Bs[2048 + tid * 8]);
    __syncthreads();
    short8 af[4], bfr[4];
#pragma unroll
    for (int i = 0; i < 4; ++i) {
      af[i]  = *(const short8*)&As[(wm + i * 16 + l16) * 32 + quad * 8];
      bfr[i] = *(const short8*)&Bs[(wn + i * 16 + l16) * 32 + quad * 8];
    }
#pragma unroll
    for (int mt = 0; mt < 4; ++mt)
#pragma unroll
      for (int nt = 0; nt < 4; ++nt)
        acc[mt][nt] = __builtin_amdgcn_mfma_f32_16x16x32_bf16(af[mt], bfr[nt], acc[mt][nt], 0, 0, 0);
    __syncthreads();
  }

  if (g == 2) {
    // V epilogue: transpose 16x16 subtiles through LDS -> Vt [B,H,64,S]
    float* tb = (float*)As + wave * 272;
#pragma unroll
    for (int mt = 0; mt < 4; ++mt)
#pragma unroll
      for (int nt = 0; nt < 4; ++nt) {
        int nbase = bn + wn + nt * 16;
        float bvv = bias[nbase + l16];
#pragma unroll
        for (int r = 0; r < 4; ++r)
          tb[(quad * 4 + r) * 17 + l16] = acc[mt][nt][r] + bvv;
        float v2[4];
#pragma unroll
        for (int r2 = 0; r2 < 4; ++r2)
          v2[r2] = tb[l16 * 17 + quad * 4 + r2];
        int m = bm + wm + mt * 16 + l16;
        int bb = m >> 11, s = m & 2047;
#pragma unroll
        for (int r2 = 0; r2 < 4; ++r2) {
          int n = nbase + quad * 4 + r2;
          int h = n >> 6, d = n & 63;
          out[((size_t)(bb * NH + h) * DK + d) * SEQ + s] = f2bf(v2[r2]);
        }
      }
    return;
  }

  const float scl = (g == 0) ? QSCALE : 1.0f;
#pragma unroll
  for (int mt = 0; mt < 4; ++mt)
#pragma unroll
    for (int nt = 0; nt < 4; ++nt) {
      int n = bn + wn + nt * 16 + l16;
      float bvv = bias[n];
#pragma unroll
      for (int r = 0; r < 4; ++r) {
        int m = bm + wm + mt * 16 + quad * 4 + r;
        float v = (acc[mt][nt][r] + bvv) * scl;
        int b = m >> 11, s = m & 2047;
        int h = n >> 6,  d = n & 63;
        out[((size_t)(b * NH + h) * SEQ + s) * DK + d] = f2bf(v);
      }
    }
}

// ---------------- output projection GEMM, 128x64 tiles (grid 512) ----------------
__global__ __launch_bounds__(256, 2) void gemm_out(
    const unsigned short* __restrict__ A,
    const unsigned short* __restrict__ Bt,
    const float* __restrict__ bias,
    float* __restrict__ out)
{
  constexpr int K = D_MODEL;
  __shared__ unsigned short As[128 * 32];
  __shared__ unsigned short Bs[64 * 32];
  const int tid  = threadIdx.x;
  const int wave = tid >> 6, lane = tid & 63;
  const int quad = lane >> 4, l16 = lane & 15;
  const int bm = blockIdx.y * 128, bn = blockIdx.x * 64;
  const int wm = (wave >> 1) * 64, wn = (wave & 1) * 32;
  const int srow = tid >> 2, scol = (tid & 3) * 8;

  f32x4 acc[4][2] = {};
  for (int k0 = 0; k0 < K; k0 += 32) {
    load16_lds(&A [(size_t)(bm      + srow) * K + k0 + scol], &As[tid * 8]);
    load16_lds(&A [(size_t)(bm + 64 + srow) * K + k0 + scol], &As[2048 + tid * 8]);
    load16_lds(&Bt[(size_t)(bn      + srow) * K + k0 + scol], &Bs[tid * 8]);
    __syncthreads();
    short8 af[4], bfr[2];
#pragma unroll
    for (int i = 0; i < 4; ++i)
      af[i]  = *(const short8*)&As[(wm + i * 16 + l16) * 32 + quad * 8];
#pragma unroll
    for (int i = 0; i < 2; ++i)
      bfr[i] = *(const short8*)&Bs[(wn + i * 16 + l16) * 32 + quad * 8];
#pragma unroll
    for (int mt = 0; mt < 4; ++mt)
#pragma unroll
      for (int nt = 0; nt < 2; ++nt)
        acc[mt][nt] = __builtin_amdgcn_mfma_f32_16x16x32_bf16(af[mt], bfr[nt], acc[mt][nt], 0, 0, 0);
    __syncthreads();
  }
#pragma unroll
  for (int mt = 0; mt < 4; ++mt)
#pragma unroll
    for (int nt = 0; nt < 2; ++nt) {
      int n = bn + wn + nt * 16 + l16;
      float bvv = bias[n];
#pragma unroll
      for (int r = 0; r < 4; ++r) {
        int m = bm + wm + mt * 16 + quad * 4 + r;
        out[(size_t)m * D_MODEL + n] = acc[mt][nt][r] + bvv;
      }
    }
}

// ---------------- flash attention v6: 32x32x16 MFMA, no P-LDS roundtrip ----------------
// 512-thread blocks (8 waves), 128 Q rows/block, grid 512. Wave pair (gr) shares
// 32 rows; hk=wave&1 takes half the keys per 64-key chunk. Sᵀ = K·Qᵀ via
// mfma_32x32x16 (C: col=lane&31=qrow, row=key=(reg&3)+8(reg>>2)+4h). P moves to
// PV A-layout IN REGISTERS via 4 v_permlane32_swap (P never touches LDS).
// LDS traffic/wave-chunk: 4 K-frag + 4 V-frag b128 reads + 2 staging writes.
// End: ctx partials merged across wave pairs through (dead) K/V LDS.
__global__ __launch_bounds__(512, 4) void attn(
    const unsigned short* __restrict__ Qh,
    const unsigned short* __restrict__ Kh,
    const unsigned short* __restrict__ Vt,
    unsigned short* __restrict__ ctx)
{
  const int blk = blockIdx.x;
  const int bh = blk >> 4, qt = blk & 15;
  const int tid = threadIdx.x;
  const int wave = tid >> 6, gr = wave >> 1, hk = wave & 1;
  const int lane = tid & 63, l32 = lane & 31, h = lane >> 5;
  const int srow = tid >> 3, su = tid & 7;

  __shared__ __align__(16) char smem[33280];
  unsigned short* Ks = (unsigned short*)smem;            // [2][64*64] swizzled [key][d]
  unsigned short* Vs = (unsigned short*)(smem + 16384);  // [2][64*64] swizzled [d][key]
  float* lbuf = (float*)(smem + 32768);                  // [4][32] denom merge

  const unsigned short* Kbase = Kh + (size_t)bh * SEQ * DK;
  const unsigned short* Vbase = Vt + (size_t)bh * DK * SEQ;
  const unsigned short* Qp = Qh + ((size_t)bh * SEQ + qt * 128 + gr * 32) * DK;

  // Q as 32x32x16 B-operand: B[n=qrow=l32][k = g*16 + h*8 + j]
  short8 qf[4];
#pragma unroll
  for (int g = 0; g < 4; ++g)
    qf[g] = *(const short8*)&Qp[l32 * DK + g * 16 + h * 8];

  f32x16 cacc[2] = {};   // ctx partial: col=d(nt*32+l32), row=qrow via reg map
  float lacc = 0.f;      // per-lane partial denominator for qrow = l32

  const int krow = hk * 32 + l32;    // this wave's K rows in the chunk

  short8 sk, sv;
  auto stage_load = [&](int c) {
    sk = *(const short8*)(Kbase + ((size_t)(c * 64 + srow)) * DK + su * 8);
    sv = *(const short8*)(Vbase + (size_t)srow * SEQ + c * 64 + su * 8);
  };
  auto stage_write = [&](int b) {
    int p = ((su + srow) & 7) * 8;
    *(short8*)&Ks[b * 4096 + srow * 64 + p] = sk;
    *(short8*)&Vs[b * 4096 + srow * 64 + p] = sv;
  };

  stage_load(0); stage_write(0);
  __syncthreads();

  for (int c = 0; c < SEQ / 64; ++c) {
    const int buf = c & 1;
    const bool pre = (c + 1 < SEQ / 64);
    if (pre) stage_load(c + 1);

    // ---- Sᵀ[key 32][qrow 32], K-dim = d (4 steps of 16)
    f32x16 s = {};
#pragma unroll
    for (int g = 0; g < 4; ++g) {
      short8 kb = *(const short8*)&Ks[buf * 4096 + krow * 64 + ((g * 2 + h + krow) & 7) * 8];
      s = __builtin_amdgcn_mfma_f32_32x32x16_bf16(kb, qf[g], s, 0, 0, 0);
    }

    // ---- p = exp2(s); per-lane denominator (qrow = l32 fixed per lane)
    float p[16];
#pragma unroll
    for (int i = 0; i < 16; ++i) p[i] = EXP2(s[i]);
    lacc += (((p[0]+p[1])+(p[2]+p[3])) + ((p[4]+p[5])+(p[6]+p[7])))
          + (((p[8]+p[9])+(p[10]+p[11])) + ((p[12]+p[13])+(p[14]+p[15])));

    // ---- pack to bf16 pairs; permlane32_swap rearranges C-layout -> A-layout
    unsigned pk[8];
#pragma unroll
    for (int i = 0; i < 8; ++i) pk[i] = pack_bf2(p[2 * i], p[2 * i + 1]);
    plswap(pk[0], pk[2], h); plswap(pk[1], pk[3], h);
    plswap(pk[4], pk[6], h); plswap(pk[5], pk[7], h);
    union { unsigned u[4]; short8 s8; } A0, A1;
    A0.u[0] = pk[0]; A0.u[1] = pk[1]; A0.u[2] = pk[2]; A0.u[3] = pk[3];
    A1.u[0] = pk[4]; A1.u[1] = pk[5]; A1.u[2] = pk[6]; A1.u[3] = pk[7];

    // ---- PV: ctx[qrow][d] += P[qrow][key-half] V[key-half][d]
#pragma unroll
    for (int nt = 0; nt < 2; ++nt) {
      int vrow = nt * 32 + l32;
      short8 vb0 = *(const short8*)&Vs[buf * 4096 + vrow * 64 + ((hk * 4 + 0 + h + vrow) & 7) * 8];
      short8 vb1 = *(const short8*)&Vs[buf * 4096 + vrow * 64 + ((hk * 4 + 2 + h + vrow) & 7) * 8];
      cacc[nt] = __builtin_amdgcn_mfma_f32_32x32x16_bf16(A0.s8, vb0, cacc[nt], 0, 0, 0);
      cacc[nt] = __builtin_amdgcn_mfma_f32_32x32x16_bf16(A1.s8, vb1, cacc[nt], 0, 0, 0);
    }

    if (pre) { stage_write(buf ^ 1); __syncthreads(); }
  }

  // ---- merge wave pairs (key halves) through LDS, then store
  lacc += __shfl_xor(lacc, 32);
  __syncthreads();                       // all K/V reads done; smem reusable
  float* mb = (float*)smem + gr * 2048;  // 8 KB per pair group
  if (hk == 1) {
#pragma unroll
    for (int nt = 0; nt < 2; ++nt)
#pragma unroll
      for (int rq = 0; rq < 4; ++rq) {
        f32x4 t;
        t[0] = cacc[nt][rq * 4 + 0]; t[1] = cacc[nt][rq * 4 + 1];
        t[2] = cacc[nt][rq * 4 + 2]; t[3] = cacc[nt][rq * 4 + 3];
        *(f32x4*)&mb[nt * 1024 + lane * 16 + rq * 4] = t;
      }
    lbuf[gr * 32 + l32] = lacc;
  }
  __syncthreads();
  if (hk == 0) {
    lacc += lbuf[gr * 32 + l32];
    float inv = 1.0f / lacc;
    float lvr[16];
#pragma unroll
    for (int r = 0; r < 16; ++r)
      lvr[r] = __shfl(inv, (r & 3) + 8 * (r >> 2) + 4 * h);
    const int b = bh >> 4, hh = bh & 15;
#pragma unroll
    for (int nt = 0; nt < 2; ++nt)
#pragma unroll
      for (int rq = 0; rq < 4; ++rq) {
        f32x4 t = *(const f32x4*)&mb[nt * 1024 + lane * 16 + rq * 4];
#pragma unroll
        for (int e = 0; e < 4; ++e) {
          int r = rq * 4 + e;
          int ql = (r & 3) + 8 * (r >> 2) + 4 * h;
          int m = qt * 128 + gr * 32 + ql;
          float val = (cacc[nt][r] + t[e]) * lvr[r];
          ctx[(size_t)(b * SEQ + m) * D_MODEL + hh * 64 + nt * 32 + l32] = f2bf(val);
        }
      }
  }
}

extern "C" void kernel_launch(void* const* d_in, const int* in_sizes, int n_in,
                              void* d_out, int out_size, void* d_ws, size_t ws_size,
                              hipStream_t stream) {
  const float* q  = (const float*)d_in[0];
  const float* k  = (const float*)d_in[1];
  const float* v  = (const float*)d_in[2];
  const float* Wq = (const float*)d_in[3];
  const float* bq = (const float*)d_in[4];
  const float* Wk = (const float*)d_in[5];
  const float* bk = (const float*)d_in[6];
  const float* Wv = (const float*)d_in[7];
  const float* bv = (const float*)d_in[8];
  const float* Wo = (const float*)d_in[9];
  const float* bo = (const float*)d_in[10];

  char* ws = (char*)d_ws;
  const size_t SZ_ACT = (size_t)MROWS * D_MODEL * 2;    // 8 MB
  const size_t SZ_W   = (size_t)D_MODEL * D_MODEL * 2;  // 2 MB
  unsigned short* qkvb = (unsigned short*)(ws);                    // 24 MB
  unsigned short* Wall = (unsigned short*)(ws + 3 * SZ_ACT);       // 8 MB
  unsigned short* Qh   = (unsigned short*)(ws + 3 * SZ_ACT + 4 * SZ_W);
  unsigned short* Kh   = (unsigned short*)(ws + 4 * SZ_ACT + 4 * SZ_W);
  unsigned short* Vt   = (unsigned short*)(ws + 5 * SZ_ACT + 4 * SZ_W);
  unsigned short* Wot  = Wall + 3 * (size_t)D_MODEL * D_MODEL;
  unsigned short* ctx  = qkvb;   // alias: qkv bf16 dead after projections

  int n4 = MROWS * D_MODEL / 4;
  cvt_all<<<dim3(n4 / 256, 3), 256, 0, stream>>>(q, k, v, qkvb, n4);
  wtrans_all<<<dim3(32, 32, 4), 256, 0, stream>>>(Wq, Wk, Wv, Wo, Wall);

  gemm_qkv<<<dim3(D_MODEL / 128, 96), 256, 0, stream>>>(qkvb, Wall, bq, bk, bv, Qh, Kh, Vt);

  attn<<<dim3(32 * 16), 512, 0, stream>>>(Qh, Kh, Vt, ctx);

  gemm_out<<<dim3(D_MODEL / 64, MROWS / 128), 256, 0, stream>>>(ctx, Wot, bo, (float*)d_out);
}

// Round 7
// 224.219 us; speedup vs baseline: 1.0474x; 1.0061x over previous
//
#include <hip/hip_runtime.h>

#define D_MODEL 1024
#define SEQ     2048
#define BATCH   2
#define NH      16
#define DK      64
#define MROWS   (BATCH*SEQ)   // 4096

typedef __attribute__((ext_vector_type(8))) short short8;    // 8 bf16 (4 VGPRs)
typedef __attribute__((ext_vector_type(4))) float f32x4;
typedef __attribute__((ext_vector_type(16))) float f32x16;

// 1/sqrt(64) * log2(e): folded into Q projection so scores feed exp2 directly
#define QSCALE 0.18033688011112042f

#if __has_builtin(__builtin_amdgcn_exp2f)
#define EXP2(x) __builtin_amdgcn_exp2f(x)
#else
#define EXP2(x) exp2f(x)
#endif

static __device__ __forceinline__ unsigned short f2bf(float f) {
  unsigned u = __float_as_uint(f);
  u += 0x7fff + ((u >> 16) & 1);          // round-to-nearest-even
  return (unsigned short)(u >> 16);
}

// pack two fp32 -> two bf16 (round-half-up) in 3 VALU via v_perm
static __device__ __forceinline__ unsigned pack_bf2(float a, float b) {
  unsigned ua = __float_as_uint(a) + 0x8000u;
  unsigned ub = __float_as_uint(b) + 0x8000u;
#if __has_builtin(__builtin_amdgcn_perm)
  return __builtin_amdgcn_perm(ub, ua, 0x07060302u);  // {ub.b3,ub.b2,ua.b3,ua.b2}
#else
  return (ua >> 16) | (ub & 0xffff0000u);
#endif
}

// v_permlane32_swap_b32: x' = {x.lo32, y.lo32}, y' = {x.hi32, y.hi32}
static __device__ __forceinline__ void plswap(unsigned& x, unsigned& y, int h) {
#if __has_builtin(__builtin_amdgcn_permlane32_swap)
  typedef __attribute__((ext_vector_type(2))) unsigned uint2v;
  uint2v r = __builtin_amdgcn_permlane32_swap(x, y, false, false);
  x = r.x; y = r.y;
#else
  unsigned xs = __shfl_xor((int)x, 32), ys = __shfl_xor((int)y, 32);
  unsigned nx = h ? ys : x;
  unsigned ny = h ? y : xs;
  x = nx; y = ny;
#endif
}

static __device__ __forceinline__ void load16_lds(const void* g, void* l) {
  __builtin_amdgcn_global_load_lds(
      (const __attribute__((address_space(1))) void*)g,
      (__attribute__((address_space(3))) void*)l, 16, 0, 0);
}

// ---------------- prep: fp32->bf16 cvt of q,k,v AND 4 weight transposes ----------------
// grid (4096, 4): y<3 -> cvt tensor y (x = 4096 blocks over 1M float4s);
// y==3 -> weight transpose, x encodes (weight, n0, k0).
__global__ void prep(const float* __restrict__ q, const float* __restrict__ k,
                     const float* __restrict__ v,
                     const float* __restrict__ Wq, const float* __restrict__ Wk,
                     const float* __restrict__ Wv, const float* __restrict__ Wo,
                     unsigned short* __restrict__ qkvb, unsigned short* __restrict__ Wall) {
  __shared__ float t[32][33];
  if (blockIdx.y < 3) {
    int i = blockIdx.x * 256 + threadIdx.x;
    const float* src = (blockIdx.y == 0) ? q : (blockIdx.y == 1) ? k : v;
    float4 val = ((const float4*)src)[i];
    unsigned r0 = (unsigned)f2bf(val.x) | ((unsigned)f2bf(val.y) << 16);
    unsigned r1 = (unsigned)f2bf(val.z) | ((unsigned)f2bf(val.w) << 16);
    uint2 u; u.x = r0; u.y = r1;
    ((uint2*)(qkvb + (size_t)blockIdx.y * MROWS * D_MODEL))[i] = u;
    return;
  }
  int x = blockIdx.x;
  int w = x >> 10, rem = x & 1023;
  int n0 = (rem >> 5) * 32, k0 = (rem & 31) * 32;
  const float* W = (w == 0) ? Wq : (w == 1) ? Wk : (w == 2) ? Wv : Wo;
  unsigned short* dst = Wall + (size_t)w * D_MODEL * D_MODEL;
  int tx = threadIdx.x & 31, ty = threadIdx.x >> 5;
#pragma unroll
  for (int i = 0; i < 32; i += 8)
    t[ty + i][tx] = W[(size_t)(k0 + ty + i) * D_MODEL + n0 + tx];
  __syncthreads();
#pragma unroll
  for (int i = 0; i < 32; i += 8)
    dst[(size_t)(n0 + ty + i) * D_MODEL + k0 + tx] = f2bf(t[tx][ty + i]);
}

// ---------------- fused QKV projection GEMM (128x128 tiles, 64-K per barrier) ----------------
// Two 32-wide K-sub-tiles staged per barrier (As[2]/Bs[2], 64 B rows stay
// conflict-free with global_load_lds's unpadded layout). 16 iterations, 32 MFMA each.
// g = blockIdx.y>>5: g==0 Q head-split pre-scaled by QSCALE; g==1 K; g==2 Vt [B,H,64,S].
__global__ __launch_bounds__(256, 2) void gemm_qkv(
    const unsigned short* __restrict__ Abig,
    const unsigned short* __restrict__ Wt,
    const float* __restrict__ bq, const float* __restrict__ bk, const float* __restrict__ bv,
    unsigned short* __restrict__ Qh, unsigned short* __restrict__ Kh,
    unsigned short* __restrict__ Vt)
{
  constexpr int K = D_MODEL;
  __shared__ unsigned short As[2][128 * 32];   // 16 KB
  __shared__ unsigned short Bs[2][128 * 32];   // 16 KB
  const int g = blockIdx.y >> 5;
  const unsigned short* A  = Abig + (size_t)g * MROWS * K;
  const unsigned short* Bt = Wt + (size_t)g * K * K;
  const float* bias = (g == 0) ? bq : (g == 1) ? bk : bv;
  unsigned short* out = (g == 0) ? Qh : (g == 1) ? Kh : Vt;

  const int tid  = threadIdx.x;
  const int wave = tid >> 6, lane = tid & 63;
  const int quad = lane >> 4, l16 = lane & 15;
  const int bm = (blockIdx.y & 31) * 128, bn = blockIdx.x * 128;
  const int wm = (wave >> 1) * 64, wn = (wave & 1) * 64;
  const int srow = tid >> 2, scol = (tid & 3) * 8;

  f32x4 acc[4][4] = {};
  for (int k0 = 0; k0 < K; k0 += 64) {
#pragma unroll
    for (int h2 = 0; h2 < 2; ++h2) {
      load16_lds(&A [(size_t)(bm      + srow) * K + k0 + h2 * 32 + scol], &As[h2][tid * 8]);
      load16_lds(&A [(size_t)(bm + 64 + srow) * K + k0 + h2 * 32 + scol], &As[h2][2048 + tid * 8]);
      load16_lds(&Bt[(size_t)(bn      + srow) * K + k0 + h2 * 32 + scol], &Bs[h2][tid * 8]);
      load16_lds(&Bt[(size_t)(bn + 64 + srow) * K + k0 + h2 * 32 + scol], &Bs[h2][2048 + tid * 8]);
    }
    __syncthreads();
#pragma unroll
    for (int h2 = 0; h2 < 2; ++h2) {
      short8 af[4], bfr[4];
#pragma unroll
      for (int i = 0; i < 4; ++i) {
        af[i]  = *(const short8*)&As[h2][(wm + i * 16 + l16) * 32 + quad * 8];
        bfr[i] = *(const short8*)&Bs[h2][(wn + i * 16 + l16) * 32 + quad * 8];
      }
#pragma unroll
      for (int mt = 0; mt < 4; ++mt)
#pragma unroll
        for (int nt = 0; nt < 4; ++nt)
          acc[mt][nt] = __builtin_amdgcn_mfma_f32_16x16x32_bf16(af[mt], bfr[nt], acc[mt][nt], 0, 0, 0);
    }
    __syncthreads();
  }

  if (g == 2) {
    // V epilogue: transpose 16x16 subtiles through LDS -> Vt [B,H,64,S]
    float* tb = (float*)As + wave * 272;
#pragma unroll
    for (int mt = 0; mt < 4; ++mt)
#pragma unroll
      for (int nt = 0; nt < 4; ++nt) {
        int nbase = bn + wn + nt * 16;
        float bvv = bias[nbase + l16];
#pragma unroll
        for (int r = 0; r < 4; ++r)
          tb[(quad * 4 + r) * 17 + l16] = acc[mt][nt][r] + bvv;
        float v2[4];
#pragma unroll
        for (int r2 = 0; r2 < 4; ++r2)
          v2[r2] = tb[l16 * 17 + quad * 4 + r2];
        int m = bm + wm + mt * 16 + l16;
        int bb = m >> 11, s = m & 2047;
#pragma unroll
        for (int r2 = 0; r2 < 4; ++r2) {
          int n = nbase + quad * 4 + r2;
          int hh = n >> 6, d = n & 63;
          out[((size_t)(bb * NH + hh) * DK + d) * SEQ + s] = f2bf(v2[r2]);
        }
      }
    return;
  }

  const float scl = (g == 0) ? QSCALE : 1.0f;
#pragma unroll
  for (int mt = 0; mt < 4; ++mt)
#pragma unroll
    for (int nt = 0; nt < 4; ++nt) {
      int n = bn + wn + nt * 16 + l16;
      float bvv = bias[n];
#pragma unroll
      for (int r = 0; r < 4; ++r) {
        int m = bm + wm + mt * 16 + quad * 4 + r;
        float v = (acc[mt][nt][r] + bvv) * scl;
        int b = m >> 11, s = m & 2047;
        int hh = n >> 6,  d = n & 63;
        out[((size_t)(b * NH + hh) * SEQ + s) * DK + d] = f2bf(v);
      }
    }
}

// ---------------- output projection GEMM, 128x64 tiles, 64-K per barrier ----------------
__global__ __launch_bounds__(256, 2) void gemm_out(
    const unsigned short* __restrict__ A,
    const unsigned short* __restrict__ Bt,
    const float* __restrict__ bias,
    float* __restrict__ out)
{
  constexpr int K = D_MODEL;
  __shared__ unsigned short As[2][128 * 32];   // 16 KB
  __shared__ unsigned short Bs[2][64 * 32];    // 8 KB
  const int tid  = threadIdx.x;
  const int wave = tid >> 6, lane = tid & 63;
  const int quad = lane >> 4, l16 = lane & 15;
  const int bm = blockIdx.y * 128, bn = blockIdx.x * 64;
  const int wm = (wave >> 1) * 64, wn = (wave & 1) * 32;
  const int srow = tid >> 2, scol = (tid & 3) * 8;

  f32x4 acc[4][2] = {};
  for (int k0 = 0; k0 < K; k0 += 64) {
#pragma unroll
    for (int h2 = 0; h2 < 2; ++h2) {
      load16_lds(&A [(size_t)(bm      + srow) * K + k0 + h2 * 32 + scol], &As[h2][tid * 8]);
      load16_lds(&A [(size_t)(bm + 64 + srow) * K + k0 + h2 * 32 + scol], &As[h2][2048 + tid * 8]);
      load16_lds(&Bt[(size_t)(bn      + srow) * K + k0 + h2 * 32 + scol], &Bs[h2][tid * 8]);
    }
    __syncthreads();
#pragma unroll
    for (int h2 = 0; h2 < 2; ++h2) {
      short8 af[4], bfr[2];
#pragma unroll
      for (int i = 0; i < 4; ++i)
        af[i]  = *(const short8*)&As[h2][(wm + i * 16 + l16) * 32 + quad * 8];
#pragma unroll
      for (int i = 0; i < 2; ++i)
        bfr[i] = *(const short8*)&Bs[h2][(wn + i * 16 + l16) * 32 + quad * 8];
#pragma unroll
      for (int mt = 0; mt < 4; ++mt)
#pragma unroll
        for (int nt = 0; nt < 2; ++nt)
          acc[mt][nt] = __builtin_amdgcn_mfma_f32_16x16x32_bf16(af[mt], bfr[nt], acc[mt][nt], 0, 0, 0);
    }
    __syncthreads();
  }
#pragma unroll
  for (int mt = 0; mt < 4; ++mt)
#pragma unroll
    for (int nt = 0; nt < 2; ++nt) {
      int n = bn + wn + nt * 16 + l16;
      float bvv = bias[n];
#pragma unroll
      for (int r = 0; r < 4; ++r) {
        int m = bm + wm + mt * 16 + quad * 4 + r;
        out[(size_t)m * D_MODEL + n] = acc[mt][nt][r] + bvv;
      }
    }
}

// ---------------- flash attention v7: 128-key chunks = 2x64 sub-chunks per barrier ----------------
// 512 threads (8 waves), 128 Q rows/block, grid 512. gr=wave>>1 owns 32 rows,
// hk=wave&1 takes key half of each sub-chunk. 16 barriers (was 32); two
// independent S->exp->pack->PV chains per iteration. P stays in registers
// (permlane32_swap C->A layout). LDS 66 KB, 2 blocks/CU.
__global__ __launch_bounds__(512, 4) void attn(
    const unsigned short* __restrict__ Qh,
    const unsigned short* __restrict__ Kh,
    const unsigned short* __restrict__ Vt,
    unsigned short* __restrict__ ctx)
{
  const int blk = blockIdx.x;
  const int bh = blk >> 4, qt = blk & 15;
  const int tid = threadIdx.x;
  const int wave = tid >> 6, gr = wave >> 1, hk = wave & 1;
  const int lane = tid & 63, l32 = lane & 31, h = lane >> 5;

  __shared__ __align__(16) char smem[66048];
  unsigned short* Ks = (unsigned short*)smem;            // [2][128*64] swizzled [key][d]
  unsigned short* Vs = (unsigned short*)(smem + 32768);  // [2][64*128] swizzled [d][key]
  float* lbuf = (float*)(smem + 65536);                  // [4][32] denom merge

  const unsigned short* Kbase = Kh + (size_t)bh * SEQ * DK;
  const unsigned short* Vbase = Vt + (size_t)bh * DK * SEQ;
  const unsigned short* Qp = Qh + ((size_t)bh * SEQ + qt * 128 + gr * 32) * DK;

  // Q as 32x32x16 B-operand: B[n=qrow=l32][k = g*16 + h*8 + j]
  short8 qf[4];
#pragma unroll
  for (int g = 0; g < 4; ++g)
    qf[g] = *(const short8*)&Qp[l32 * DK + g * 16 + h * 8];

  f32x16 cacc[2] = {};   // ctx partial: col=d(nt*32+l32), row=qrow via reg map
  float lacc = 0.f;      // per-lane partial denominator for qrow = l32

  // staging: K 128 rows x 64 d (8 16B-units/row); V 64 rows x 128 keys (16 units/row)
  const int kr0 = tid >> 3, uk = tid & 7;
  const int vr0 = tid >> 4, uv = tid & 15;

  short8 sk0, sk1, sv0, sv1;
  auto stage_load = [&](int c) {
    const unsigned short* kg = Kbase + (size_t)(c * 128 + kr0) * DK + uk * 8;
    sk0 = *(const short8*)kg;
    sk1 = *(const short8*)(kg + (size_t)64 * DK);
    const unsigned short* vg = Vbase + (size_t)vr0 * SEQ + c * 128 + uv * 8;
    sv0 = *(const short8*)vg;
    sv1 = *(const short8*)(vg + (size_t)32 * SEQ);
  };
  auto stage_write = [&](int b) {
    int pk_ = ((uk + kr0) & 7) * 8;                // (kr0+64)&7 == kr0&7
    *(short8*)&Ks[b * 8192 + kr0 * 64 + pk_]        = sk0;
    *(short8*)&Ks[b * 8192 + (kr0 + 64) * 64 + pk_] = sk1;
    int pv_ = ((uv + vr0) & 15) * 8;               // (vr0+32)&15 == vr0&15
    *(short8*)&Vs[b * 8192 + vr0 * 128 + pv_]        = sv0;
    *(short8*)&Vs[b * 8192 + (vr0 + 32) * 128 + pv_] = sv1;
  };

  stage_load(0); stage_write(0);
  __syncthreads();

  for (int c = 0; c < SEQ / 128; ++c) {
    const int buf = c & 1;
    const bool pre = (c + 1 < SEQ / 128);
    if (pre) stage_load(c + 1);

#pragma unroll
    for (int sc = 0; sc < 2; ++sc) {
      const int krow = sc * 64 + hk * 32 + l32;
      // ---- Sᵀ[key 32][qrow 32], K-dim = d (4 steps of 16)
      f32x16 s = {};
#pragma unroll
      for (int g = 0; g < 4; ++g) {
        short8 kb = *(const short8*)&Ks[buf * 8192 + krow * 64 + ((g * 2 + h + krow) & 7) * 8];
        s = __builtin_amdgcn_mfma_f32_32x32x16_bf16(kb, qf[g], s, 0, 0, 0);
      }

      // ---- p = exp2(s); per-lane denominator
      float p[16];
#pragma unroll
      for (int i = 0; i < 16; ++i) p[i] = EXP2(s[i]);
      lacc += (((p[0]+p[1])+(p[2]+p[3])) + ((p[4]+p[5])+(p[6]+p[7])))
            + (((p[8]+p[9])+(p[10]+p[11])) + ((p[12]+p[13])+(p[14]+p[15])));

      // ---- pack bf16; permlane32_swap rearranges C-layout -> A-layout
      unsigned pk[8];
#pragma unroll
      for (int i = 0; i < 8; ++i) pk[i] = pack_bf2(p[2 * i], p[2 * i + 1]);
      plswap(pk[0], pk[2], h); plswap(pk[1], pk[3], h);
      plswap(pk[4], pk[6], h); plswap(pk[5], pk[7], h);
      union { unsigned u[4]; short8 s8; } A0, A1;
      A0.u[0] = pk[0]; A0.u[1] = pk[1]; A0.u[2] = pk[2]; A0.u[3] = pk[3];
      A1.u[0] = pk[4]; A1.u[1] = pk[5]; A1.u[2] = pk[6]; A1.u[3] = pk[7];

      // ---- PV: ctx[qrow][d] += P[qrow][key-half] V[key-half][d]
#pragma unroll
      for (int nt = 0; nt < 2; ++nt) {
        int vrow = nt * 32 + l32;
        short8 vb0 = *(const short8*)&Vs[buf * 8192 + vrow * 128 + ((sc * 8 + hk * 4 + 0 + h + vrow) & 15) * 8];
        short8 vb1 = *(const short8*)&Vs[buf * 8192 + vrow * 128 + ((sc * 8 + hk * 4 + 2 + h + vrow) & 15) * 8];
        cacc[nt] = __builtin_amdgcn_mfma_f32_32x32x16_bf16(A0.s8, vb0, cacc[nt], 0, 0, 0);
        cacc[nt] = __builtin_amdgcn_mfma_f32_32x32x16_bf16(A1.s8, vb1, cacc[nt], 0, 0, 0);
      }
    }

    if (pre) { stage_write(buf ^ 1); __syncthreads(); }
  }

  // ---- merge wave pairs (key halves) through LDS, then store
  lacc += __shfl_xor(lacc, 32);
  __syncthreads();                       // all K/V reads done; smem reusable
  float* mb = (float*)smem + gr * 2048;  // 8 KB per pair group
  if (hk == 1) {
#pragma unroll
    for (int nt = 0; nt < 2; ++nt)
#pragma unroll
      for (int rq = 0; rq < 4; ++rq) {
        f32x4 t;
        t[0] = cacc[nt][rq * 4 + 0]; t[1] = cacc[nt][rq * 4 + 1];
        t[2] = cacc[nt][rq * 4 + 2]; t[3] = cacc[nt][rq * 4 + 3];
        *(f32x4*)&mb[nt * 1024 + lane * 16 + rq * 4] = t;
      }
    lbuf[gr * 32 + l32] = lacc;
  }
  __syncthreads();
  if (hk == 0) {
    lacc += lbuf[gr * 32 + l32];
    float inv = 1.0f / lacc;
    float lvr[16];
#pragma unroll
    for (int r = 0; r < 16; ++r)
      lvr[r] = __shfl(inv, (r & 3) + 8 * (r >> 2) + 4 * h);
    const int b = bh >> 4, hh = bh & 15;
#pragma unroll
    for (int nt = 0; nt < 2; ++nt)
#pragma unroll
      for (int rq = 0; rq < 4; ++rq) {
        f32x4 t = *(const f32x4*)&mb[nt * 1024 + lane * 16 + rq * 4];
#pragma unroll
        for (int e = 0; e < 4; ++e) {
          int r = rq * 4 + e;
          int ql = (r & 3) + 8 * (r >> 2) + 4 * h;
          int m = qt * 128 + gr * 32 + ql;
          float val = (cacc[nt][r] + t[e]) * lvr[r];
          ctx[(size_t)(b * SEQ + m) * D_MODEL + hh * 64 + nt * 32 + l32] = f2bf(val);
        }
      }
  }
}

extern "C" void kernel_launch(void* const* d_in, const int* in_sizes, int n_in,
                              void* d_out, int out_size, void* d_ws, size_t ws_size,
                              hipStream_t stream) {
  const float* q  = (const float*)d_in[0];
  const float* k  = (const float*)d_in[1];
  const float* v  = (const float*)d_in[2];
  const float* Wq = (const float*)d_in[3];
  const float* bq = (const float*)d_in[4];
  const float* Wk = (const float*)d_in[5];
  const float* bk = (const float*)d_in[6];
  const float* Wv = (const float*)d_in[7];
  const float* bv = (const float*)d_in[8];
  const float* Wo = (const float*)d_in[9];
  const float* bo = (const float*)d_in[10];

  char* ws = (char*)d_ws;
  const size_t SZ_ACT = (size_t)MROWS * D_MODEL * 2;    // 8 MB
  const size_t SZ_W   = (size_t)D_MODEL * D_MODEL * 2;  // 2 MB
  unsigned short* qkvb = (unsigned short*)(ws);                    // 24 MB
  unsigned short* Wall = (unsigned short*)(ws + 3 * SZ_ACT);       // 8 MB
  unsigned short* Qh   = (unsigned short*)(ws + 3 * SZ_ACT + 4 * SZ_W);
  unsigned short* Kh   = (unsigned short*)(ws + 4 * SZ_ACT + 4 * SZ_W);
  unsigned short* Vt   = (unsigned short*)(ws + 5 * SZ_ACT + 4 * SZ_W);
  unsigned short* Wot  = Wall + 3 * (size_t)D_MODEL * D_MODEL;
  unsigned short* ctx  = qkvb;   // alias: qkv bf16 dead after projections

  prep<<<dim3(4096, 4), 256, 0, stream>>>(q, k, v, Wq, Wk, Wv, Wo, qkvb, Wall);

  gemm_qkv<<<dim3(D_MODEL / 128, 96), 256, 0, stream>>>(qkvb, Wall, bq, bk, bv, Qh, Kh, Vt);

  attn<<<dim3(32 * 16), 512, 0, stream>>>(Qh, Kh, Vt, ctx);

  gemm_out<<<dim3(D_MODEL / 64, MROWS / 128), 256, 0, stream>>>(ctx, Wot, bo, (float*)d_out);
}